// Round 17
// baseline (645.390 us; speedup 1.0000x reference)
//
#include <hip/hip_runtime.h>
#include <math.h>

#define TPB 256
typedef unsigned short u16;
typedef _Float16 v8h __attribute__((ext_vector_type(8)));
typedef float v4f __attribute__((ext_vector_type(4)));

__device__ __forceinline__ u16 f2h(float v) {
    return __builtin_bit_cast(u16, (_Float16)v);
}
__device__ __forceinline__ float h2f(u16 v) {
    return (float)__builtin_bit_cast(_Float16, v);
}

typedef const __attribute__((address_space(1))) unsigned int* gp1_t;
typedef __attribute__((address_space(3))) unsigned int* lp3_t;
__device__ __forceinline__ void gload_lds16(const void* g, void* l) {
    __builtin_amdgcn_global_load_lds((gp1_t)g, (lp3_t)l, 16, 0, 0);
}

// ---------------------------------------------------------------------------
// weight cast + permute: OIHW fp32 -> [co][ky*3+kx][ci] f16  (conv weights)
// ---------------------------------------------------------------------------
__global__ __launch_bounds__(256) void cast_perm_k(
    const float* __restrict__ src, u16* __restrict__ dst, int Cout, int Cin)
{
    int i = blockIdx.x * TPB + threadIdx.x;
    int total = Cout * Cin * 9;
    if (i >= total) return;
    int ci = i % Cin, rest = i / Cin;
    int w = rest % 9, co = rest / 9;
    dst[i] = f2h(src[(co * Cin + ci) * 9 + w]);
}

// offset-conv weight fold: W'[co][w][ci] = f16(W*A[ci]), obias[co] = sum W*B[ci]
__global__ __launch_bounds__(256) void scale_off_w_k(
    const float* __restrict__ src, const float* __restrict__ sfin,
    u16* __restrict__ dst, float* __restrict__ obias, int Cin)
{
    int co = blockIdx.x, t = threadIdx.x;
    int n = Cin * 9;
    float acc = 0.f;
    for (int i = t; i < n; i += TPB) {
        int ci = i % Cin, w = i / Cin;
        float wv = src[((size_t)co * Cin + ci) * 9 + w];
        dst[(size_t)co * n + i] = f2h(wv * sfin[2 * ci]);
        acc += wv * sfin[2 * ci + 1];
    }
    __shared__ float r[TPB];
    r[t] = acc;
    __syncthreads();
    for (int d = 128; d > 0; d >>= 1) {
        if (t < d) r[t] += r[t + d];
        __syncthreads();
    }
    if (t == 0) obias[co] = r[0];
}

__global__ void zero_k(float* p, int n)
{
    int i = blockIdx.x * TPB + threadIdx.x;
    if (i < n) p[i] = 0.f;
}

// fill the 1-pixel halo ring with per-channel value (VAL table or 0)
__global__ __launch_bounds__(256) void halo_fill_k(
    u16* __restrict__ buf, const u16* __restrict__ VAL, int Wpad, int Hpad,
    int C, int Clog, size_t astride, int perimg)
{
    int idx = blockIdx.x * TPB + threadIdx.x;
    int img = blockIdx.y;
    if (idx >= perimg) return;
    int hp = idx >> Clog, c = idx & (C - 1);
    int y, x;
    if (hp < Wpad) { y = 0; x = hp; }
    else if (hp < 2 * Wpad) { y = Hpad - 1; x = hp - Wpad; }
    else { int r = hp - 2 * Wpad; y = 1 + (r >> 1); x = (r & 1) ? (Wpad - 1) : 0; }
    buf[(size_t)img * astride + ((size_t)y * Wpad + x) * C + c] =
        VAL ? VAL[c] : (u16)0;
}

// per-channel v0 = f16(-B/A): the raw value whose BN image is 0
__global__ void make_v0_k(const float* __restrict__ sfin, u16* __restrict__ v0,
                          int C)
{
    int c = threadIdx.x;
    if (c >= C) return;
    float A = sfin[2 * c], B = sfin[2 * c + 1];
    v0[c] = (fabsf(A) > 1e-20f) ? f2h(-B / A) : (u16)0;
}

// reduce 16-way split stats -> per-channel affine; resets slots it read.
__global__ void reduce_stats_k(
    const float* __restrict__ stats2c, const float* __restrict__ g,
    const float* __restrict__ b, float* __restrict__ sfin, int C, float invcnt)
{
    float* stats2 = (float*)stats2c;
    int c = threadIdx.x;
    if (c >= C) return;
    float s = 0.f, s2 = 0.f;
#pragma unroll
    for (int k = 0; k < 16; ++k) {
        s  += stats2[k * 256 + 2 * c];
        s2 += stats2[k * 256 + 2 * c + 1];
        stats2[k * 256 + 2 * c] = 0.f;
        stats2[k * 256 + 2 * c + 1] = 0.f;
    }
    float mean = s * invcnt;
    float var  = fmaxf(s2 * invcnt - mean * mean, 0.f);
    float A = g[c] / sqrtf(var + 1e-5f);
    sfin[2 * c] = A;
    sfin[2 * c + 1] = b[c] - mean * A;
}

// ---------------------------------------------------------------------------
// Implicit-GEMM conv from HALO'ed NHWC f16 act. 2-buffer LDS pipeline
// (R8/R9-proven equal to 3-buffer) — shared block is a UNION of the pipeline
// buffers and the epilogue transpose tile, cutting LDS 48->33/40 KB for
// 4 blocks/CU (the MODE-1 epilogue is gather-latency-bound; more TLP).
// MODE 1: fused BN-folded offset-conv + bilinear deform, affine at write.
// MODE 2: conv -> bias+relu + fused stats -> raw halo'ed NHWC f16.
// MODE 3: conv -> bias+relu + fused stats + per-(img,ch) GAP sums only.
// ---------------------------------------------------------------------------
template <int WGM, int WGN, int MODE>
__global__ __launch_bounds__(256) void gemm_impl_k(
    const u16* __restrict__ A, const u16* __restrict__ act,
    u16* __restrict__ outd, const float* __restrict__ bias,
    float* __restrict__ stats2, float* __restrict__ pooled,
    const float* __restrict__ sfin,
    int M, int K, int Npix, int Cin, int CPWlog, int Wpad, int Wolog,
    int stride, size_t astride, int WpadO, size_t ostride)
{
    constexpr int BM = WGM * 64, BN = WGN * 64;
    constexpr int ASLOTS = BM / 16, BSLOTS = BN / 16;
    constexpr int SLOTS = ASLOTS + BSLOTS, SPW = SLOTS / 4;
    constexpr int HALF = (BM + BN) * 32;            // one pipeline buffer (u16)
    constexpr int TRANS = BM * (BN + 2);            // epilogue transpose tile
    constexpr int LSZ = (2 * HALF > TRANS) ? 2 * HALF : TRANS;
    __shared__ u16 lds[LSZ];
    const int t = threadIdx.x, lane = t & 63, wave = t >> 6;
    const int g = blockIdx.z;
    const int p0 = blockIdx.x * BN, m0 = blockIdx.y * BM;
    const u16* actg = act + (size_t)g * astride;
    const int Wo = 1 << Wolog;

    const u16* src[SPW];
#pragma unroll
    for (int i = 0; i < SPW; ++i) {
        int s = wave * SPW + i;
        if (s < ASLOTS) {
            int ch = s * 64 + lane, nr = ch >> 2, cst = ch & 3;
            int csrc = cst ^ ((nr >> 1) & 3);
            src[i] = A + (size_t)(m0 + nr) * K + csrc * 8;
        } else {
            int ch = (s - ASLOTS) * 64 + lane, nr = ch >> 2, cst = ch & 3;
            int csrc = cst ^ ((nr >> 1) & 3);
            int p = p0 + nr, oy = p >> Wolog, ox = p & (Wo - 1);
            src[i] = actg + (size_t)(oy * stride * Wpad + ox * stride) * Cin + csrc * 8;
        }
    }

    auto issue = [&](int kk, int buf) {
        int k0 = kk << 5;
        int w = kk >> CPWlog;
        int ci0 = (kk & ((1 << CPWlog) - 1)) << 5;
        int koff = (w / 3 * Wpad + w % 3) * Cin + ci0;
#pragma unroll
        for (int i = 0; i < SPW; ++i) {
            int s = wave * SPW + i;
            const u16* sp = src[i] + ((s < ASLOTS) ? k0 : koff);
            gload_lds16(sp, lds + buf * HALF + s * 512);
        }
    };

    v4f acc[4][4];
#pragma unroll
    for (int mi = 0; mi < 4; ++mi)
#pragma unroll
        for (int ni = 0; ni < 4; ++ni) acc[mi][ni] = (v4f){0.f, 0.f, 0.f, 0.f};

    const int wm = wave % WGM, wn = wave / WGM;
    const int la = lane & 15, quad = lane >> 4;

    issue(0, 0);
    const int nk = K >> 5;
    for (int kk = 0; kk < nk; ++kk) {
        int buf = kk & 1;
        asm volatile("s_waitcnt vmcnt(0)\n\ts_barrier" ::: "memory");
        if (kk + 1 < nk) issue(kk + 1, buf ^ 1);
        const u16* Lb = lds + buf * HALF;
        v8h a[4], b[4];
#pragma unroll
        for (int mi = 0; mi < 4; ++mi) {
            int r = wm * 64 + mi * 16 + la;
            a[mi] = *(const v8h*)(Lb + (r * 4 + (quad ^ ((r >> 1) & 3))) * 8);
        }
#pragma unroll
        for (int ni = 0; ni < 4; ++ni) {
            int r = wn * 64 + ni * 16 + la;
            b[ni] = *(const v8h*)(Lb + BM * 32 + (r * 4 + (quad ^ ((r >> 1) & 3))) * 8);
        }
#pragma unroll
        for (int mi = 0; mi < 4; ++mi)
#pragma unroll
            for (int ni = 0; ni < 4; ++ni)
                acc[mi][ni] = __builtin_amdgcn_mfma_f32_16x16x32_f16(
                    a[mi], b[ni], acc[mi][ni], 0, 0, 0);
    }

    if constexpr (MODE == 1) {
        // ---- fused deform epilogue (BN-folded offsets; affine at write) ----
        constexpr int LP = BN + 2;
        u16* S = lds;
        __syncthreads();
#pragma unroll
        for (int mi = 0; mi < 4; ++mi)
#pragma unroll
            for (int r = 0; r < 4; ++r) {
                int rl = wm * 64 + mi * 16 + quad * 4 + r;
                float bv = bias[m0 + rl];
#pragma unroll
                for (int ni = 0; ni < 4; ++ni) {
                    int cl = wn * 64 + ni * 16 + la;
                    S[rl * LP + cl] = f2h(acc[mi][ni][r] + bv);
                }
            }
        __syncthreads();
        const int HWh = Npix >> 1;
        const int Ho = Npix >> Wolog;
        const int lane32 = t & 31, grp = t >> 5;
        const int cbase = m0 >> 1;
        constexpr int CCH = (BM / 2 + 31) / 32;
        constexpr int JPG = (BN / 2) / 8;
        u16* og = outd + (size_t)g * astride;
#pragma unroll
        for (int b = 0; b < 2; ++b) {
#pragma unroll
            for (int jj = 0; jj < JPG; ++jj) {
                int j = grp * JPG + jj;
                int p = b * HWh + (p0 >> 1) + j;
                int yy = p >> Wolog, xx = p & (Wo - 1);
#pragma unroll
                for (int cc = 0; cc < CCH; ++cc) {
                    int cl32 = cc * 32 + lane32;
                    int c = cbase + cl32;
                    int rl = 2 * cl32 + b;
                    float dy = h2f(S[rl * LP + 2 * j]);
                    float dx = h2f(S[rl * LP + 2 * j + 1]);
                    float cy = fminf(fmaxf((float)yy + dy, 0.f), (float)(Ho - 1));
                    float cx = fminf(fmaxf((float)xx + dx, 0.f), (float)(Wo - 1));
                    float y0f = floorf(cy), x0f = floorf(cx);
                    float ty = cy - y0f, tx = cx - x0f;
                    int y0 = (int)y0f, y1 = (int)ceilf(cy);
                    int x0 = (int)x0f, x1 = (int)ceilf(cx);
                    float vlt = h2f(actg[((size_t)(y0 + 1) * Wpad + (x0 + 1)) * Cin + c]);
                    float vrt = h2f(actg[((size_t)(y1 + 1) * Wpad + (x0 + 1)) * Cin + c]);
                    float vlb = h2f(actg[((size_t)(y0 + 1) * Wpad + (x1 + 1)) * Cin + c]);
                    float vrb = h2f(actg[((size_t)(y1 + 1) * Wpad + (x1 + 1)) * Cin + c]);
                    float vt = ty * (vrt - vlt) + vlt;
                    float vb = ty * (vrb - vlb) + vlb;
                    float2 ab = ((const float2*)sfin)[c];
                    og[((size_t)(yy + 1) * Wpad + (xx + 1)) * Cin + c] =
                        f2h(ab.x * (tx * (vb - vt) + vt) + ab.y);
                }
            }
        }
    } else if constexpr (MODE == 2) {
        // ---- conv -> NHWC f16 (raw, pre-BN) + fused stats ----
        float* ST = stats2 + (((blockIdx.x ^ blockIdx.z) & 15) * 256);
#pragma unroll
        for (int mi = 0; mi < 4; ++mi) {
#pragma unroll
            for (int r = 0; r < 4; ++r) {
                int row = m0 + wm * 64 + mi * 16 + quad * 4 + r;
                float bv = bias[row];
                float s = 0.f, s2 = 0.f;
#pragma unroll
                for (int ni = 0; ni < 4; ++ni) {
                    float v = fmaxf(acc[mi][ni][r] + bv, 0.f);
                    acc[mi][ni][r] = v;
                    s += v;
                    s2 += v * v;
                }
#pragma unroll
                for (int m = 1; m < 16; m <<= 1) {
                    s  += __shfl_xor(s, m);
                    s2 += __shfl_xor(s2, m);
                }
                if (la == 0) {
                    atomicAdd(&ST[2 * row], s);
                    atomicAdd(&ST[2 * row + 1], s2);
                }
            }
        }
        constexpr int LP = BN + 2;
        u16* S = lds;
        __syncthreads();
#pragma unroll
        for (int mi = 0; mi < 4; ++mi)
#pragma unroll
            for (int r = 0; r < 4; ++r) {
                int rl = wm * 64 + mi * 16 + quad * 4 + r;
#pragma unroll
                for (int ni = 0; ni < 4; ++ni) {
                    int cl = wn * 64 + ni * 16 + la;
                    S[rl * LP + cl] = f2h(acc[mi][ni][r]);
                }
            }
        __syncthreads();
        const int lane32 = t & 31, grp = t >> 5;
        constexpr int CCH = BM / 32;
        constexpr int JPG = BN / 8;
        u16* og = outd + (size_t)g * ostride;
#pragma unroll
        for (int jj = 0; jj < JPG; ++jj) {
            int j = grp * JPG + jj;
            int p = p0 + j;
            int yy = p >> Wolog, xx = p & (Wo - 1);
            u16* orow = og + ((size_t)(yy + 1) * WpadO + (xx + 1)) * M + m0;
#pragma unroll
            for (int cc = 0; cc < CCH; ++cc) {
                int rl = cc * 32 + lane32;
                orow[rl] = S[rl * LP + j];
            }
        }
    } else {
        // ---- MODE 3: stats + per-(img,ch) GAP sums only ----
        float* ST = stats2 + (((blockIdx.x ^ blockIdx.z) & 15) * 256);
        float* PL = pooled + (size_t)g * M;
#pragma unroll
        for (int mi = 0; mi < 4; ++mi) {
#pragma unroll
            for (int r = 0; r < 4; ++r) {
                int row = m0 + wm * 64 + mi * 16 + quad * 4 + r;
                float bv = bias[row];
                float s = 0.f, s2 = 0.f;
#pragma unroll
                for (int ni = 0; ni < 4; ++ni) {
                    float v = fmaxf(acc[mi][ni][r] + bv, 0.f);
                    s += v;
                    s2 += v * v;
                }
#pragma unroll
                for (int m = 1; m < 16; m <<= 1) {
                    s  += __shfl_xor(s, m);
                    s2 += __shfl_xor(s2, m);
                }
                if (la == 0) {
                    atomicAdd(&ST[2 * row], s);
                    atomicAdd(&ST[2 * row + 1], s2);
                    atomicAdd(&PL[row], s);
                }
            }
        }
    }
}

// ---------------------------------------------------------------------------
// conv11 (Cin=1, 1->32, 128x128, s1) direct -> halo'ed NHWC f16 (raw)
// ---------------------------------------------------------------------------
__global__ __launch_bounds__(256) void conv11_nhwc_k(
    const float* __restrict__ in, const float* __restrict__ wgt,
    const float* __restrict__ bias, u16* __restrict__ out, size_t astride)
{
    __shared__ float tile[18 * 18];
    __shared__ float wl[288];
    __shared__ float bl[32];
    const int t = threadIdx.x;
    const int tx = t & 15, ty = t >> 4;
    const int img = blockIdx.z;
    const int ox0 = blockIdx.x << 4, oy0 = blockIdx.y << 4;
    for (int i = t; i < 288; i += TPB) wl[i] = wgt[i];
    if (t < 32) bl[t] = bias[t];
    const float* inI = in + (size_t)img * 16384;
    for (int i = t; i < 18 * 18; i += TPB) {
        int r = i / 18, c = i - r * 18;
        int yy = oy0 + r - 1, xx = ox0 + c - 1;
        float v = 0.f;
        if (yy >= 0 && yy < 128 && xx >= 0 && xx < 128) v = inI[yy * 128 + xx];
        tile[i] = v;
    }
    __syncthreads();
    float nb[9];
#pragma unroll
    for (int ky = 0; ky < 3; ++ky)
#pragma unroll
        for (int kx = 0; kx < 3; ++kx)
            nb[ky * 3 + kx] = tile[(ty + ky) * 18 + tx + kx];
    unsigned int pk[16];
#pragma unroll
    for (int c = 0; c < 32; ++c) {
        const float* w9 = wl + c * 9;
        float v = bl[c];
#pragma unroll
        for (int k = 0; k < 9; ++k) v += nb[k] * w9[k];
        v = fmaxf(v, 0.f);
        u16 h = f2h(v);
        if (c & 1) pk[c >> 1] |= (unsigned int)h << 16;
        else       pk[c >> 1] = h;
    }
    u16* og = out + (size_t)img * astride +
              ((size_t)(oy0 + ty + 1) * 130 + (ox0 + tx + 1)) * 32;
#pragma unroll
    for (int q = 0; q < 4; ++q)
        *(uint4*)(og + q * 8) = *(uint4*)&pk[q * 4];
}

// stage-1 BN stats from halo'ed NHWC f16 (C=32, 128x128, Wpad=130)
__global__ __launch_bounds__(256) void bn_stats_nhwc_k(
    const u16* __restrict__ buf, float* __restrict__ stats2, size_t astride)
{
    int img = blockIdx.y;
    int c = threadIdx.x & 31, pg = threadIdx.x >> 5;
    const u16* bi = buf + (size_t)img * astride;
    float s = 0.f, s2 = 0.f;
    int pend = (blockIdx.x + 1) << 10;
    for (int p = (blockIdx.x << 10) + pg; p < pend; p += 8) {
        int y = p >> 7, x = p & 127;
        float v = h2f(bi[((size_t)(y + 1) * 130 + (x + 1)) * 32 + c]);
        s += v;
        s2 += v * v;
    }
    __shared__ float r1[256], r2[256];
    r1[threadIdx.x] = s;
    r2[threadIdx.x] = s2;
    __syncthreads();
    for (int d = 4; d >= 1; d >>= 1) {
        if (pg < d) {
            r1[threadIdx.x] += r1[threadIdx.x + d * 32];
            r2[threadIdx.x] += r2[threadIdx.x + d * 32];
        }
        __syncthreads();
    }
    if (threadIdx.x < 32) {
        float* ST = stats2 + ((blockIdx.x & 15) * 256);
        atomicAdd(&ST[2 * c], r1[c]);
        atomicAdd(&ST[2 * c + 1], r2[c]);
    }
}

// FC + softmax, applying bn22 affine to the raw GAP sums inline.
__global__ __launch_bounds__(64) void fc_softmax_bn_k(
    const float* __restrict__ pooled, const float* __restrict__ sfin,
    const float* __restrict__ fw, const float* __restrict__ fb,
    float* __restrict__ outp)
{
    int n = blockIdx.x;
    __shared__ float logits[10];
    int k = threadIdx.x;
    if (k < 10) {
        float s = fb[k];
        const float* pr = pooled + n * 128;
        const float* wr = fw + k * 128;
        for (int c = 0; c < 128; ++c) {
            float v = sfin[2 * c] * (pr[c] * (1.f / 1024.f)) + sfin[2 * c + 1];
            s += v * wr[c];
        }
        logits[k] = s;
    }
    __syncthreads();
    if (k < 10) {
        float m = logits[0];
#pragma unroll
        for (int j = 1; j < 10; ++j) m = fmaxf(m, logits[j]);
        float den = 0.f;
#pragma unroll
        for (int j = 0; j < 10; ++j) den += expf(logits[j] - m);
        outp[n * 10 + k] = expf(logits[k] - m) / den;
    }
}

// ---------------------------------------------------------------------------
extern "C" void kernel_launch(void* const* d_in, const int* in_sizes, int n_in,
                              void* d_out, int out_size, void* d_ws, size_t ws_size,
                              hipStream_t stream)
{
    const float* x     = (const float*)d_in[0];
    const float* c11w  = (const float*)d_in[1];
    const float* c11b  = (const float*)d_in[2];
    const float* bn11g = (const float*)d_in[3];
    const float* bn11b = (const float*)d_in[4];
    const float* o12w  = (const float*)d_in[5];
    const float* c12w  = (const float*)d_in[6];
    const float* c12b  = (const float*)d_in[7];
    const float* bn12g = (const float*)d_in[8];
    const float* bn12b = (const float*)d_in[9];
    const float* o21w  = (const float*)d_in[10];
    const float* c21w  = (const float*)d_in[11];
    const float* c21b  = (const float*)d_in[12];
    const float* bn21g = (const float*)d_in[13];
    const float* bn21b = (const float*)d_in[14];
    const float* o22w  = (const float*)d_in[15];
    const float* c22w  = (const float*)d_in[16];
    const float* c22b  = (const float*)d_in[17];
    const float* bn22g = (const float*)d_in[18];
    const float* bn22b = (const float*)d_in[19];
    const float* fcw   = (const float*)d_in[20];
    const float* fcb   = (const float*)d_in[21];
    float* outp = (float*)d_out;

    const int N = 32;
    float* ws      = (float*)d_ws;
    u16*   ACTB0   = (u16*)(ws + 16777216);       // 18,874,368 u16 (36 MB)
    u16*   ACTB1   = (u16*)(ws + 26214400);       // 18,874,368 u16 (36 MB)
    u16*   WBF     = (u16*)(ws + 35651584);       // conv weights (f16)
    u16*   WOFF    = WBF + 368640;                // 294,912 u16 (off weights)
    float* STATS2  = ws + 35984384;               // 4096 (16 x 256)
    float* SFIN    = STATS2 + 4096;               // 256
    float* POOLED  = SFIN + 256;                  // 4096
    float* OBIAS   = POOLED + 4096;               // 256
    u16*   V0      = (u16*)(OBIAS + 256);         // 128

    u16* wc12 = WBF + 0;
    u16* wc21 = WBF + 18432;
    u16* wc22 = WBF + 92160;

    auto halo_fill = [&](u16* p, const u16* val, int Wpad, int Hpad, int C,
                         int Clog, size_t astride) {
        int perimg = (2 * Wpad + 2 * (Hpad - 2)) * C;
        dim3 g((perimg + TPB - 1) / TPB, N);
        halo_fill_k<<<g, TPB, 0, stream>>>(p, val, Wpad, Hpad, C, Clog,
                                           astride, perimg);
    };
    auto reduce_stats = [&](const float* g_, const float* b_, int C, float invcnt) {
        reduce_stats_k<<<1, 128, 0, stream>>>(STATS2, g_, b_, SFIN, C, invcnt);
    };
    auto fold_off = [&](const float* wsrc, int Cout, int Cin) {
        scale_off_w_k<<<Cout, TPB, 0, stream>>>(wsrc, SFIN, WOFF, OBIAS, Cin);
        make_v0_k<<<1, 128, 0, stream>>>(SFIN, V0, Cin);
    };

    auto cast = [&](const float* s, u16* d, int Cout, int Cin) {
        int n = Cout * Cin * 9;
        cast_perm_k<<<(n + TPB - 1) / TPB, TPB, 0, stream>>>(s, d, Cout, Cin);
    };
    cast(c12w, wc12, 64, 32);
    cast(c21w, wc21, 128, 64);
    cast(c22w, wc22, 128, 128);

    auto gemm_nhwc = [&](const u16* A, const u16* actb, u16* outb,
                         const float* bias, int M, int K, int Npix, int Cin,
                         int CPWlog, int Wpad, int Wolog, int stride,
                         size_t astride, int WpadO, size_t ostride) {
        if (M == 64) {
            dim3 g(Npix / 256, 1, N);
            gemm_impl_k<1, 4, 2><<<g, TPB, 0, stream>>>(A, actb, outb, bias,
                STATS2, nullptr, nullptr, M, K, Npix, Cin, CPWlog, Wpad, Wolog,
                stride, astride, WpadO, ostride);
        } else {
            dim3 g(Npix / 128, M / 128, N);
            gemm_impl_k<2, 2, 2><<<g, TPB, 0, stream>>>(A, actb, outb, bias,
                STATS2, nullptr, nullptr, M, K, Npix, Cin, CPWlog, Wpad, Wolog,
                stride, astride, WpadO, ostride);
        }
    };
    auto deform_stage = [&](int C, int HWlog, int Wlog, int Wpad,
                            size_t astride, int K, int CPWlog) {
        int HW = 1 << HWlog;
        int M = 2 * C;
        if (M == 64) {
            dim3 g(HW / 256, 1, N);
            gemm_impl_k<1, 4, 1><<<g, TPB, 0, stream>>>(WOFF, ACTB0, ACTB1,
                OBIAS, nullptr, nullptr, SFIN, M, K, HW, C, CPWlog, Wpad, Wlog,
                1, astride, 0, 0);
        } else {
            dim3 g(HW / 128, M / 128, N);
            gemm_impl_k<2, 2, 1><<<g, TPB, 0, stream>>>(WOFF, ACTB0, ACTB1,
                OBIAS, nullptr, nullptr, SFIN, M, K, HW, C, CPWlog, Wpad, Wlog,
                1, astride, 0, 0);
        }
    };

    const size_t AS1 = 540800;   // 130*130*32
    const size_t AS2 = 278784;   // 66*66*64
    const size_t AS3 = 557568;   // 66*66*128

    halo_fill(ACTB1, nullptr, 130, 130, 32, 5, AS1);
    zero_k<<<34, TPB, 0, stream>>>(STATS2, 8704);

    // ---- conv11 direct -> halo'ed NHWC f16 (raw); stats; fold off12 ----
    {
        dim3 g(8, 8, N);
        conv11_nhwc_k<<<g, TPB, 0, stream>>>(x, c11w, c11b, ACTB0, AS1);
    }
    {
        dim3 g(16, N);
        bn_stats_nhwc_k<<<g, TPB, 0, stream>>>(ACTB0, STATS2, AS1);
    }
    reduce_stats(bn11g, bn11b, 32, 1.f / 524288.f);
    fold_off(o12w, 64, 32);
    halo_fill(ACTB0, V0, 130, 130, 32, 5, AS1);

    // ---- fused off12+deform12: ACTB0 -> ACTB1 (AS1) ----
    deform_stage(32, 14, 7, 130, AS1, 288, 0);
    // ---- conv12 (32->64, s2) -> ACTB0 raw NHWC f16 (AS2) + stats ----
    gemm_nhwc(wc12, ACTB1, ACTB0, c12b, 64, 288, 4096, 32, 0, 130, 6, 2,
              AS1, 66, AS2);
    halo_fill(ACTB1, nullptr, 66, 66, 64, 6, AS2);
    reduce_stats(bn12g, bn12b, 64, 1.f / 131072.f);
    fold_off(o21w, 128, 64);
    halo_fill(ACTB0, V0, 66, 66, 64, 6, AS2);

    // ---- fused off21+deform21: ACTB0 -> ACTB1 (AS2) ----
    deform_stage(64, 12, 6, 66, AS2, 576, 1);
    // ---- conv21 (64->128, s1) -> ACTB0 raw NHWC f16 (AS3) + stats ----
    gemm_nhwc(wc21, ACTB1, ACTB0, c21b, 128, 576, 4096, 64, 1, 66, 6, 1,
              AS2, 66, AS3);
    halo_fill(ACTB1, nullptr, 66, 66, 128, 7, AS3);
    reduce_stats(bn21g, bn21b, 128, 1.f / 131072.f);
    fold_off(o22w, 256, 128);
    halo_fill(ACTB0, V0, 66, 66, 128, 7, AS3);

    // ---- fused off22+deform22: ACTB0 -> ACTB1 (AS3) ----
    deform_stage(128, 12, 6, 66, AS3, 1152, 2);
    // ---- conv22 (128->128, s2): stats + GAP sums only (MODE 3) ----
    {
        dim3 g(1024 / 128, 1, N);
        gemm_impl_k<2, 2, 3><<<g, TPB, 0, stream>>>(wc22, ACTB1, nullptr,
            c22b, STATS2, POOLED, nullptr, 128, 1152, 1024, 128, 2, 66, 5, 2,
            AS3, 0, 0);
    }
    reduce_stats(bn22g, bn22b, 128, 1.f / 32768.f);

    // ---- FC (+bn22 affine) + softmax ----
    fc_softmax_bn_k<<<N, 64, 0, stream>>>(POOLED, SFIN, fcw, fcb, outp);
}

// Round 18
// 612.977 us; speedup vs baseline: 1.0529x; 1.0529x over previous
//
#include <hip/hip_runtime.h>
#include <math.h>

#define TPB 256
typedef unsigned short u16;
typedef _Float16 v8h __attribute__((ext_vector_type(8)));
typedef float v4f __attribute__((ext_vector_type(4)));

__device__ __forceinline__ u16 f2h(float v) {
    return __builtin_bit_cast(u16, (_Float16)v);
}
__device__ __forceinline__ float h2f(u16 v) {
    return (float)__builtin_bit_cast(_Float16, v);
}

typedef const __attribute__((address_space(1))) unsigned int* gp1_t;
typedef __attribute__((address_space(3))) unsigned int* lp3_t;
__device__ __forceinline__ void gload_lds16(const void* g, void* l) {
    __builtin_amdgcn_global_load_lds((gp1_t)g, (lp3_t)l, 16, 0, 0);
}

// ---------------------------------------------------------------------------
// weight cast + permute: OIHW fp32 -> [co][ky*3+kx][ci] f16  (conv weights)
// ---------------------------------------------------------------------------
__global__ __launch_bounds__(256) void cast_perm_k(
    const float* __restrict__ src, u16* __restrict__ dst, int Cout, int Cin)
{
    int i = blockIdx.x * TPB + threadIdx.x;
    int total = Cout * Cin * 9;
    if (i >= total) return;
    int ci = i % Cin, rest = i / Cin;
    int w = rest % 9, co = rest / 9;
    dst[i] = f2h(src[(co * Cin + ci) * 9 + w]);
}

// offset-conv weight fold: W'[co][w][ci] = f16(W*A[ci]), obias[co] = sum W*B[ci]
__global__ __launch_bounds__(256) void scale_off_w_k(
    const float* __restrict__ src, const float* __restrict__ sfin,
    u16* __restrict__ dst, float* __restrict__ obias, int Cin)
{
    int co = blockIdx.x, t = threadIdx.x;
    int n = Cin * 9;
    float acc = 0.f;
    for (int i = t; i < n; i += TPB) {
        int ci = i % Cin, w = i / Cin;
        float wv = src[((size_t)co * Cin + ci) * 9 + w];
        dst[(size_t)co * n + i] = f2h(wv * sfin[2 * ci]);
        acc += wv * sfin[2 * ci + 1];
    }
    __shared__ float r[TPB];
    r[t] = acc;
    __syncthreads();
    for (int d = 128; d > 0; d >>= 1) {
        if (t < d) r[t] += r[t + d];
        __syncthreads();
    }
    if (t == 0) obias[co] = r[0];
}

__global__ void zero_k(float* p, int n)
{
    int i = blockIdx.x * TPB + threadIdx.x;
    if (i < n) p[i] = 0.f;
}

// fill the 1-pixel halo ring with per-channel value (VAL table or 0)
__global__ __launch_bounds__(256) void halo_fill_k(
    u16* __restrict__ buf, const u16* __restrict__ VAL, int Wpad, int Hpad,
    int C, int Clog, size_t astride, int perimg)
{
    int idx = blockIdx.x * TPB + threadIdx.x;
    int img = blockIdx.y;
    if (idx >= perimg) return;
    int hp = idx >> Clog, c = idx & (C - 1);
    int y, x;
    if (hp < Wpad) { y = 0; x = hp; }
    else if (hp < 2 * Wpad) { y = Hpad - 1; x = hp - Wpad; }
    else { int r = hp - 2 * Wpad; y = 1 + (r >> 1); x = (r & 1) ? (Wpad - 1) : 0; }
    buf[(size_t)img * astride + ((size_t)y * Wpad + x) * C + c] =
        VAL ? VAL[c] : (u16)0;
}

// per-channel v0 = f16(-B/A): the raw value whose BN image is 0
__global__ void make_v0_k(const float* __restrict__ sfin, u16* __restrict__ v0,
                          int C)
{
    int c = threadIdx.x;
    if (c >= C) return;
    float A = sfin[2 * c], B = sfin[2 * c + 1];
    v0[c] = (fabsf(A) > 1e-20f) ? f2h(-B / A) : (u16)0;
}

// reduce 16-way split stats -> per-channel affine; resets slots it read.
__global__ void reduce_stats_k(
    const float* __restrict__ stats2c, const float* __restrict__ g,
    const float* __restrict__ b, float* __restrict__ sfin, int C, float invcnt)
{
    float* stats2 = (float*)stats2c;
    int c = threadIdx.x;
    if (c >= C) return;
    float s = 0.f, s2 = 0.f;
#pragma unroll
    for (int k = 0; k < 16; ++k) {
        s  += stats2[k * 256 + 2 * c];
        s2 += stats2[k * 256 + 2 * c + 1];
        stats2[k * 256 + 2 * c] = 0.f;
        stats2[k * 256 + 2 * c + 1] = 0.f;
    }
    float mean = s * invcnt;
    float var  = fmaxf(s2 * invcnt - mean * mean, 0.f);
    float A = g[c] / sqrtf(var + 1e-5f);
    sfin[2 * c] = A;
    sfin[2 * c + 1] = b[c] - mean * A;
}

// ---------------------------------------------------------------------------
// Implicit-GEMM conv from HALO'ed NHWC f16 act. 3-buffer LDS pipeline
// (R16-proven best). XOR-swizzled frags.
// MODE 1: fused BN-folded offset-conv + bilinear deform, affine at write.
//   Per-channel (A,B) staged to LDS once per block (cuts gather-loop VGPR
//   pressure vs R16's hoisted global float2 loads).
// MODE 2: conv -> bias+relu + fused stats -> raw halo'ed NHWC f16.
// MODE 3: conv -> bias+relu + fused stats + per-(img,ch) GAP sums only.
// ---------------------------------------------------------------------------
template <int WGM, int WGN, int MODE>
__global__ __launch_bounds__(256) void gemm_impl_k(
    const u16* __restrict__ A, const u16* __restrict__ act,
    u16* __restrict__ outd, const float* __restrict__ bias,
    float* __restrict__ stats2, float* __restrict__ pooled,
    const float* __restrict__ sfin,
    int M, int K, int Npix, int Cin, int CPWlog, int Wpad, int Wolog,
    int stride, size_t astride, int WpadO, size_t ostride)
{
    constexpr int BM = WGM * 64, BN = WGN * 64;
    constexpr int ASLOTS = BM / 16, BSLOTS = BN / 16;
    constexpr int SLOTS = ASLOTS + BSLOTS, SPW = SLOTS / 4;
    __shared__ u16 lds[3][(BM + BN) * 32];
    const int t = threadIdx.x, lane = t & 63, wave = t >> 6;
    const int g = blockIdx.z;
    const int p0 = blockIdx.x * BN, m0 = blockIdx.y * BM;
    const u16* actg = act + (size_t)g * astride;
    const int Wo = 1 << Wolog;

    const u16* src[SPW];
#pragma unroll
    for (int i = 0; i < SPW; ++i) {
        int s = wave * SPW + i;
        if (s < ASLOTS) {
            int ch = s * 64 + lane, nr = ch >> 2, cst = ch & 3;
            int csrc = cst ^ ((nr >> 1) & 3);
            src[i] = A + (size_t)(m0 + nr) * K + csrc * 8;
        } else {
            int ch = (s - ASLOTS) * 64 + lane, nr = ch >> 2, cst = ch & 3;
            int csrc = cst ^ ((nr >> 1) & 3);
            int p = p0 + nr, oy = p >> Wolog, ox = p & (Wo - 1);
            src[i] = actg + (size_t)(oy * stride * Wpad + ox * stride) * Cin + csrc * 8;
        }
    }

    auto issue = [&](int kk, int buf) {
        int k0 = kk << 5;
        int w = kk >> CPWlog;
        int ci0 = (kk & ((1 << CPWlog) - 1)) << 5;
        int koff = (w / 3 * Wpad + w % 3) * Cin + ci0;
#pragma unroll
        for (int i = 0; i < SPW; ++i) {
            int s = wave * SPW + i;
            const u16* sp = src[i] + ((s < ASLOTS) ? k0 : koff);
            gload_lds16(sp, lds[buf] + s * 512);
        }
    };

    v4f acc[4][4];
#pragma unroll
    for (int mi = 0; mi < 4; ++mi)
#pragma unroll
        for (int ni = 0; ni < 4; ++ni) acc[mi][ni] = (v4f){0.f, 0.f, 0.f, 0.f};

    const int wm = wave % WGM, wn = wave / WGM;
    const int la = lane & 15, quad = lane >> 4;

    issue(0, 0);
    issue(1, 1);
    const int nk = K >> 5;
    int rb = 0, wb = 2;
    for (int kk = 0; kk < nk; ++kk) {
        if (kk + 1 < nk) {
            if constexpr (SPW == 4)
                asm volatile("s_waitcnt vmcnt(4)\n\ts_barrier" ::: "memory");
            else if constexpr (SPW == 5)
                asm volatile("s_waitcnt vmcnt(5)\n\ts_barrier" ::: "memory");
            else
                asm volatile("s_waitcnt vmcnt(0)\n\ts_barrier" ::: "memory");
            if (kk + 2 < nk) issue(kk + 2, wb);
        } else {
            asm volatile("s_waitcnt vmcnt(0)\n\ts_barrier" ::: "memory");
        }
        const u16* Lb = lds[rb];
        v8h a[4], b[4];
#pragma unroll
        for (int mi = 0; mi < 4; ++mi) {
            int r = wm * 64 + mi * 16 + la;
            a[mi] = *(const v8h*)(Lb + (r * 4 + (quad ^ ((r >> 1) & 3))) * 8);
        }
#pragma unroll
        for (int ni = 0; ni < 4; ++ni) {
            int r = wn * 64 + ni * 16 + la;
            b[ni] = *(const v8h*)(Lb + BM * 32 + (r * 4 + (quad ^ ((r >> 1) & 3))) * 8);
        }
#pragma unroll
        for (int mi = 0; mi < 4; ++mi)
#pragma unroll
            for (int ni = 0; ni < 4; ++ni)
                acc[mi][ni] = __builtin_amdgcn_mfma_f32_16x16x32_f16(
                    a[mi], b[ni], acc[mi][ni], 0, 0, 0);
        rb = (rb == 2) ? 0 : rb + 1;
        wb = (wb == 2) ? 0 : wb + 1;
    }

    if constexpr (MODE == 1) {
        // ---- fused deform epilogue (BN-folded offsets; affine at write) ----
        constexpr int LP = BN + 2;
        u16* S = &lds[0][0];
        float2* ABs = (float2*)(S + BM * LP);   // staged (A,B) per channel
        __syncthreads();
#pragma unroll
        for (int mi = 0; mi < 4; ++mi)
#pragma unroll
            for (int r = 0; r < 4; ++r) {
                int rl = wm * 64 + mi * 16 + quad * 4 + r;
                float bv = bias[m0 + rl];
#pragma unroll
                for (int ni = 0; ni < 4; ++ni) {
                    int cl = wn * 64 + ni * 16 + la;
                    S[rl * LP + cl] = f2h(acc[mi][ni][r] + bv);
                }
            }
        if (t < BM / 2) ABs[t] = ((const float2*)sfin)[(m0 >> 1) + t];
        __syncthreads();
        const int HWh = Npix >> 1;
        const int Ho = Npix >> Wolog;
        const int lane32 = t & 31, grp = t >> 5;
        const int cbase = m0 >> 1;
        constexpr int CCH = (BM / 2 + 31) / 32;
        constexpr int JPG = (BN / 2) / 8;
        u16* og = outd + (size_t)g * astride;
#pragma unroll
        for (int b = 0; b < 2; ++b) {
#pragma unroll
            for (int jj = 0; jj < JPG; ++jj) {
                int j = grp * JPG + jj;
                int p = b * HWh + (p0 >> 1) + j;
                int yy = p >> Wolog, xx = p & (Wo - 1);
#pragma unroll
                for (int cc = 0; cc < CCH; ++cc) {
                    int cl32 = cc * 32 + lane32;
                    int c = cbase + cl32;
                    int rl = 2 * cl32 + b;
                    float dy = h2f(S[rl * LP + 2 * j]);
                    float dx = h2f(S[rl * LP + 2 * j + 1]);
                    float cy = fminf(fmaxf((float)yy + dy, 0.f), (float)(Ho - 1));
                    float cx = fminf(fmaxf((float)xx + dx, 0.f), (float)(Wo - 1));
                    float y0f = floorf(cy), x0f = floorf(cx);
                    float ty = cy - y0f, tx = cx - x0f;
                    int y0 = (int)y0f, y1 = (int)ceilf(cy);
                    int x0 = (int)x0f, x1 = (int)ceilf(cx);
                    float vlt = h2f(actg[((size_t)(y0 + 1) * Wpad + (x0 + 1)) * Cin + c]);
                    float vrt = h2f(actg[((size_t)(y1 + 1) * Wpad + (x0 + 1)) * Cin + c]);
                    float vlb = h2f(actg[((size_t)(y0 + 1) * Wpad + (x1 + 1)) * Cin + c]);
                    float vrb = h2f(actg[((size_t)(y1 + 1) * Wpad + (x1 + 1)) * Cin + c]);
                    float vt = ty * (vrt - vlt) + vlt;
                    float vb = ty * (vrb - vlb) + vlb;
                    float2 ab = ABs[cl32];
                    og[((size_t)(yy + 1) * Wpad + (xx + 1)) * Cin + c] =
                        f2h(ab.x * (tx * (vb - vt) + vt) + ab.y);
                }
            }
        }
    } else if constexpr (MODE == 2) {
        // ---- conv -> NHWC f16 (raw, pre-BN) + fused stats ----
        float* ST = stats2 + (((blockIdx.x ^ blockIdx.z) & 15) * 256);
#pragma unroll
        for (int mi = 0; mi < 4; ++mi) {
#pragma unroll
            for (int r = 0; r < 4; ++r) {
                int row = m0 + wm * 64 + mi * 16 + quad * 4 + r;
                float bv = bias[row];
                float s = 0.f, s2 = 0.f;
#pragma unroll
                for (int ni = 0; ni < 4; ++ni) {
                    float v = fmaxf(acc[mi][ni][r] + bv, 0.f);
                    acc[mi][ni][r] = v;
                    s += v;
                    s2 += v * v;
                }
#pragma unroll
                for (int m = 1; m < 16; m <<= 1) {
                    s  += __shfl_xor(s, m);
                    s2 += __shfl_xor(s2, m);
                }
                if (la == 0) {
                    atomicAdd(&ST[2 * row], s);
                    atomicAdd(&ST[2 * row + 1], s2);
                }
            }
        }
        constexpr int LP = BN + 2;
        u16* S = &lds[0][0];
        __syncthreads();
#pragma unroll
        for (int mi = 0; mi < 4; ++mi)
#pragma unroll
            for (int r = 0; r < 4; ++r) {
                int rl = wm * 64 + mi * 16 + quad * 4 + r;
#pragma unroll
                for (int ni = 0; ni < 4; ++ni) {
                    int cl = wn * 64 + ni * 16 + la;
                    S[rl * LP + cl] = f2h(acc[mi][ni][r]);
                }
            }
        __syncthreads();
        const int lane32 = t & 31, grp = t >> 5;
        constexpr int CCH = BM / 32;
        constexpr int JPG = BN / 8;
        u16* og = outd + (size_t)g * ostride;
#pragma unroll
        for (int jj = 0; jj < JPG; ++jj) {
            int j = grp * JPG + jj;
            int p = p0 + j;
            int yy = p >> Wolog, xx = p & (Wo - 1);
            u16* orow = og + ((size_t)(yy + 1) * WpadO + (xx + 1)) * M + m0;
#pragma unroll
            for (int cc = 0; cc < CCH; ++cc) {
                int rl = cc * 32 + lane32;
                orow[rl] = S[rl * LP + j];
            }
        }
    } else {
        // ---- MODE 3: stats + per-(img,ch) GAP sums only ----
        float* ST = stats2 + (((blockIdx.x ^ blockIdx.z) & 15) * 256);
        float* PL = pooled + (size_t)g * M;
#pragma unroll
        for (int mi = 0; mi < 4; ++mi) {
#pragma unroll
            for (int r = 0; r < 4; ++r) {
                int row = m0 + wm * 64 + mi * 16 + quad * 4 + r;
                float bv = bias[row];
                float s = 0.f, s2 = 0.f;
#pragma unroll
                for (int ni = 0; ni < 4; ++ni) {
                    float v = fmaxf(acc[mi][ni][r] + bv, 0.f);
                    s += v;
                    s2 += v * v;
                }
#pragma unroll
                for (int m = 1; m < 16; m <<= 1) {
                    s  += __shfl_xor(s, m);
                    s2 += __shfl_xor(s2, m);
                }
                if (la == 0) {
                    atomicAdd(&ST[2 * row], s);
                    atomicAdd(&ST[2 * row + 1], s2);
                    atomicAdd(&PL[row], s);
                }
            }
        }
    }
}

// ---------------------------------------------------------------------------
// conv11 (Cin=1, 1->32, 128x128, s1) direct -> halo'ed NHWC f16 (raw)
// ---------------------------------------------------------------------------
__global__ __launch_bounds__(256) void conv11_nhwc_k(
    const float* __restrict__ in, const float* __restrict__ wgt,
    const float* __restrict__ bias, u16* __restrict__ out, size_t astride)
{
    __shared__ float tile[18 * 18];
    __shared__ float wl[288];
    __shared__ float bl[32];
    const int t = threadIdx.x;
    const int tx = t & 15, ty = t >> 4;
    const int img = blockIdx.z;
    const int ox0 = blockIdx.x << 4, oy0 = blockIdx.y << 4;
    for (int i = t; i < 288; i += TPB) wl[i] = wgt[i];
    if (t < 32) bl[t] = bias[t];
    const float* inI = in + (size_t)img * 16384;
    for (int i = t; i < 18 * 18; i += TPB) {
        int r = i / 18, c = i - r * 18;
        int yy = oy0 + r - 1, xx = ox0 + c - 1;
        float v = 0.f;
        if (yy >= 0 && yy < 128 && xx >= 0 && xx < 128) v = inI[yy * 128 + xx];
        tile[i] = v;
    }
    __syncthreads();
    float nb[9];
#pragma unroll
    for (int ky = 0; ky < 3; ++ky)
#pragma unroll
        for (int kx = 0; kx < 3; ++kx)
            nb[ky * 3 + kx] = tile[(ty + ky) * 18 + tx + kx];
    unsigned int pk[16];
#pragma unroll
    for (int c = 0; c < 32; ++c) {
        const float* w9 = wl + c * 9;
        float v = bl[c];
#pragma unroll
        for (int k = 0; k < 9; ++k) v += nb[k] * w9[k];
        v = fmaxf(v, 0.f);
        u16 h = f2h(v);
        if (c & 1) pk[c >> 1] |= (unsigned int)h << 16;
        else       pk[c >> 1] = h;
    }
    u16* og = out + (size_t)img * astride +
              ((size_t)(oy0 + ty + 1) * 130 + (ox0 + tx + 1)) * 32;
#pragma unroll
    for (int q = 0; q < 4; ++q)
        *(uint4*)(og + q * 8) = *(uint4*)&pk[q * 4];
}

// stage-1 BN stats from halo'ed NHWC f16 (C=32, 128x128, Wpad=130)
__global__ __launch_bounds__(256) void bn_stats_nhwc_k(
    const u16* __restrict__ buf, float* __restrict__ stats2, size_t astride)
{
    int img = blockIdx.y;
    int c = threadIdx.x & 31, pg = threadIdx.x >> 5;
    const u16* bi = buf + (size_t)img * astride;
    float s = 0.f, s2 = 0.f;
    int pend = (blockIdx.x + 1) << 10;
    for (int p = (blockIdx.x << 10) + pg; p < pend; p += 8) {
        int y = p >> 7, x = p & 127;
        float v = h2f(bi[((size_t)(y + 1) * 130 + (x + 1)) * 32 + c]);
        s += v;
        s2 += v * v;
    }
    __shared__ float r1[256], r2[256];
    r1[threadIdx.x] = s;
    r2[threadIdx.x] = s2;
    __syncthreads();
    for (int d = 4; d >= 1; d >>= 1) {
        if (pg < d) {
            r1[threadIdx.x] += r1[threadIdx.x + d * 32];
            r2[threadIdx.x] += r2[threadIdx.x + d * 32];
        }
        __syncthreads();
    }
    if (threadIdx.x < 32) {
        float* ST = stats2 + ((blockIdx.x & 15) * 256);
        atomicAdd(&ST[2 * c], r1[c]);
        atomicAdd(&ST[2 * c + 1], r2[c]);
    }
}

// FC + softmax, applying bn22 affine to the raw GAP sums inline.
__global__ __launch_bounds__(64) void fc_softmax_bn_k(
    const float* __restrict__ pooled, const float* __restrict__ sfin,
    const float* __restrict__ fw, const float* __restrict__ fb,
    float* __restrict__ outp)
{
    int n = blockIdx.x;
    __shared__ float logits[10];
    int k = threadIdx.x;
    if (k < 10) {
        float s = fb[k];
        const float* pr = pooled + n * 128;
        const float* wr = fw + k * 128;
        for (int c = 0; c < 128; ++c) {
            float v = sfin[2 * c] * (pr[c] * (1.f / 1024.f)) + sfin[2 * c + 1];
            s += v * wr[c];
        }
        logits[k] = s;
    }
    __syncthreads();
    if (k < 10) {
        float m = logits[0];
#pragma unroll
        for (int j = 1; j < 10; ++j) m = fmaxf(m, logits[j]);
        float den = 0.f;
#pragma unroll
        for (int j = 0; j < 10; ++j) den += expf(logits[j] - m);
        outp[n * 10 + k] = expf(logits[k] - m) / den;
    }
}

// ---------------------------------------------------------------------------
extern "C" void kernel_launch(void* const* d_in, const int* in_sizes, int n_in,
                              void* d_out, int out_size, void* d_ws, size_t ws_size,
                              hipStream_t stream)
{
    const float* x     = (const float*)d_in[0];
    const float* c11w  = (const float*)d_in[1];
    const float* c11b  = (const float*)d_in[2];
    const float* bn11g = (const float*)d_in[3];
    const float* bn11b = (const float*)d_in[4];
    const float* o12w  = (const float*)d_in[5];
    const float* c12w  = (const float*)d_in[6];
    const float* c12b  = (const float*)d_in[7];
    const float* bn12g = (const float*)d_in[8];
    const float* bn12b = (const float*)d_in[9];
    const float* o21w  = (const float*)d_in[10];
    const float* c21w  = (const float*)d_in[11];
    const float* c21b  = (const float*)d_in[12];
    const float* bn21g = (const float*)d_in[13];
    const float* bn21b = (const float*)d_in[14];
    const float* o22w  = (const float*)d_in[15];
    const float* c22w  = (const float*)d_in[16];
    const float* c22b  = (const float*)d_in[17];
    const float* bn22g = (const float*)d_in[18];
    const float* bn22b = (const float*)d_in[19];
    const float* fcw   = (const float*)d_in[20];
    const float* fcb   = (const float*)d_in[21];
    float* outp = (float*)d_out;

    const int N = 32;
    float* ws      = (float*)d_ws;
    u16*   ACTB0   = (u16*)(ws + 16777216);       // 18,874,368 u16 (36 MB)
    u16*   ACTB1   = (u16*)(ws + 26214400);       // 18,874,368 u16 (36 MB)
    u16*   WBF     = (u16*)(ws + 35651584);       // conv weights (f16)
    u16*   WOFF    = WBF + 368640;                // 294,912 u16 (off weights)
    float* STATS2  = ws + 35984384;               // 4096 (16 x 256)
    float* SFIN    = STATS2 + 4096;               // 256
    float* POOLED  = SFIN + 256;                  // 4096
    float* OBIAS   = POOLED + 4096;               // 256
    u16*   V0      = (u16*)(OBIAS + 256);         // 128

    u16* wc12 = WBF + 0;
    u16* wc21 = WBF + 18432;
    u16* wc22 = WBF + 92160;

    auto halo_fill = [&](u16* p, const u16* val, int Wpad, int Hpad, int C,
                         int Clog, size_t astride) {
        int perimg = (2 * Wpad + 2 * (Hpad - 2)) * C;
        dim3 g((perimg + TPB - 1) / TPB, N);
        halo_fill_k<<<g, TPB, 0, stream>>>(p, val, Wpad, Hpad, C, Clog,
                                           astride, perimg);
    };
    auto reduce_stats = [&](const float* g_, const float* b_, int C, float invcnt) {
        reduce_stats_k<<<1, 128, 0, stream>>>(STATS2, g_, b_, SFIN, C, invcnt);
    };
    auto fold_off = [&](const float* wsrc, int Cout, int Cin) {
        scale_off_w_k<<<Cout, TPB, 0, stream>>>(wsrc, SFIN, WOFF, OBIAS, Cin);
        make_v0_k<<<1, 128, 0, stream>>>(SFIN, V0, Cin);
    };

    auto cast = [&](const float* s, u16* d, int Cout, int Cin) {
        int n = Cout * Cin * 9;
        cast_perm_k<<<(n + TPB - 1) / TPB, TPB, 0, stream>>>(s, d, Cout, Cin);
    };
    cast(c12w, wc12, 64, 32);
    cast(c21w, wc21, 128, 64);
    cast(c22w, wc22, 128, 128);

    auto gemm_nhwc = [&](const u16* A, const u16* actb, u16* outb,
                         const float* bias, int M, int K, int Npix, int Cin,
                         int CPWlog, int Wpad, int Wolog, int stride,
                         size_t astride, int WpadO, size_t ostride) {
        if (M == 64) {
            dim3 g(Npix / 256, 1, N);
            gemm_impl_k<1, 4, 2><<<g, TPB, 0, stream>>>(A, actb, outb, bias,
                STATS2, nullptr, nullptr, M, K, Npix, Cin, CPWlog, Wpad, Wolog,
                stride, astride, WpadO, ostride);
        } else {
            dim3 g(Npix / 128, M / 128, N);
            gemm_impl_k<2, 2, 2><<<g, TPB, 0, stream>>>(A, actb, outb, bias,
                STATS2, nullptr, nullptr, M, K, Npix, Cin, CPWlog, Wpad, Wolog,
                stride, astride, WpadO, ostride);
        }
    };
    auto deform_stage = [&](int C, int HWlog, int Wlog, int Wpad,
                            size_t astride, int K, int CPWlog) {
        int HW = 1 << HWlog;
        int M = 2 * C;
        if (M == 64) {
            dim3 g(HW / 256, 1, N);
            gemm_impl_k<1, 4, 1><<<g, TPB, 0, stream>>>(WOFF, ACTB0, ACTB1,
                OBIAS, nullptr, nullptr, SFIN, M, K, HW, C, CPWlog, Wpad, Wlog,
                1, astride, 0, 0);
        } else {
            dim3 g(HW / 128, M / 128, N);
            gemm_impl_k<2, 2, 1><<<g, TPB, 0, stream>>>(WOFF, ACTB0, ACTB1,
                OBIAS, nullptr, nullptr, SFIN, M, K, HW, C, CPWlog, Wpad, Wlog,
                1, astride, 0, 0);
        }
    };

    const size_t AS1 = 540800;   // 130*130*32
    const size_t AS2 = 278784;   // 66*66*64
    const size_t AS3 = 557568;   // 66*66*128

    halo_fill(ACTB1, nullptr, 130, 130, 32, 5, AS1);
    zero_k<<<34, TPB, 0, stream>>>(STATS2, 8704);

    // ---- conv11 direct -> halo'ed NHWC f16 (raw); stats; fold off12 ----
    {
        dim3 g(8, 8, N);
        conv11_nhwc_k<<<g, TPB, 0, stream>>>(x, c11w, c11b, ACTB0, AS1);
    }
    {
        dim3 g(16, N);
        bn_stats_nhwc_k<<<g, TPB, 0, stream>>>(ACTB0, STATS2, AS1);
    }
    reduce_stats(bn11g, bn11b, 32, 1.f / 524288.f);
    fold_off(o12w, 64, 32);
    halo_fill(ACTB0, V0, 130, 130, 32, 5, AS1);

    // ---- fused off12+deform12: ACTB0 -> ACTB1 (AS1) ----
    deform_stage(32, 14, 7, 130, AS1, 288, 0);
    // ---- conv12 (32->64, s2) -> ACTB0 raw NHWC f16 (AS2) + stats ----
    gemm_nhwc(wc12, ACTB1, ACTB0, c12b, 64, 288, 4096, 32, 0, 130, 6, 2,
              AS1, 66, AS2);
    halo_fill(ACTB1, nullptr, 66, 66, 64, 6, AS2);
    reduce_stats(bn12g, bn12b, 64, 1.f / 131072.f);
    fold_off(o21w, 128, 64);
    halo_fill(ACTB0, V0, 66, 66, 64, 6, AS2);

    // ---- fused off21+deform21: ACTB0 -> ACTB1 (AS2) ----
    deform_stage(64, 12, 6, 66, AS2, 576, 1);
    // ---- conv21 (64->128, s1) -> ACTB0 raw NHWC f16 (AS3) + stats ----
    gemm_nhwc(wc21, ACTB1, ACTB0, c21b, 128, 576, 4096, 64, 1, 66, 6, 1,
              AS2, 66, AS3);
    halo_fill(ACTB1, nullptr, 66, 66, 128, 7, AS3);
    reduce_stats(bn21g, bn21b, 128, 1.f / 131072.f);
    fold_off(o22w, 256, 128);
    halo_fill(ACTB0, V0, 66, 66, 128, 7, AS3);

    // ---- fused off22+deform22: ACTB0 -> ACTB1 (AS3) ----
    deform_stage(128, 12, 6, 66, AS3, 1152, 2);
    // ---- conv22 (128->128, s2): stats + GAP sums only (MODE 3) ----
    {
        dim3 g(1024 / 128, 1, N);
        gemm_impl_k<2, 2, 3><<<g, TPB, 0, stream>>>(wc22, ACTB1, nullptr,
            c22b, STATS2, POOLED, nullptr, 128, 1152, 1024, 128, 2, 66, 5, 2,
            AS3, 0, 0);
    }
    reduce_stats(bn22g, bn22b, 128, 1.f / 32768.f);

    // ---- FC (+bn22 affine) + softmax ----
    fc_softmax_bn_k<<<N, 64, 0, stream>>>(POOLED, SFIN, fcw, fcb, outp);
}